// Round 9
// baseline (4778.836 us; speedup 1.0000x reference)
//
#include <hip/hip_runtime.h>
#include <hip/hip_bf16.h>

// Problem constants: B=64, T=2048, IN_F=128, H1=OUT_F=64, 4H=256
#define BB 64
#define TT 2048
#define INF 128
#define HH 64
#define GG 256  // 4*H

__device__ __forceinline__ float sigm(float x) { return 1.0f / (1.0f + __expf(-x)); }
__device__ __forceinline__ float tanh_f(float x) {
  float e = __expf(2.0f * x);
  return 1.0f - 2.0f / (e + 1.0f);
}
// Wave-uniform broadcast of lane l's value via v_readlane (SGPR path, no LDS).
__device__ __forceinline__ float bcast(float v, int l) {
  return __uint_as_float(__builtin_amdgcn_readlane(__float_as_uint(v), l));
}

// ---------------------------------------------------------------------------
// Rounds 6-8 hit a gfx950 backend ICE (V_CMP_NE_U32 src_shared_base) in the
// instruction-interleaved dual-sequence kernel; three rewrites could not
// isolate the construct. This round implements the SAME diagnostic using
// ONLY round-3's proven-to-compile constructs: 32 blocks x 512 threads =
// TWO complete r3 pipelines per block (seq A = wids 0-3, seq B = wids 4-7).
// Waves map to SIMDs round-robin (wid&3), so W0_A and W0_B share SIMD0 and
// W2_A/W2_B share SIMD3: the HARDWARE wave scheduler interleaves the two
// recurrence streams, filling each stream's stall cycles with the other's
// issue (m114: co-resident waves overlap, time ~ max not sum).
// Diagnostic fork: win => recurrence stalls were latency-type;
// null => issue/throughput-bound => next round cuts instruction count
// (inline-asm dot with AGPR-direct v_fmac operands).
// All LDS arrays/flags are STATICALLY NAMED, accessed as direct lvalues via
// r3's WAITC/PUBLISH macros; no pointer selects, no runtime array selection.
// Per-seq k-accumulation order unchanged -> bit-identical numerics.
// ---------------------------------------------------------------------------

// Full 4-gate weight load: lane owns rows lane / 64+lane / 128+lane / 192+lane.
#define WL1(I)                                                                  \
  { float4 a = p[lane * 16 + (I)];                                              \
    wi[4*(I)] = a.x; wi[4*(I)+1] = a.y; wi[4*(I)+2] = a.z; wi[4*(I)+3] = a.w;   \
    float4 c = p[(64 + lane) * 16 + (I)];                                       \
    wf[4*(I)] = c.x; wf[4*(I)+1] = c.y; wf[4*(I)+2] = c.z; wf[4*(I)+3] = c.w;   \
    float4 d = p[(128 + lane) * 16 + (I)];                                      \
    wg[4*(I)] = d.x; wg[4*(I)+1] = d.y; wg[4*(I)+2] = d.z; wg[4*(I)+3] = d.w;   \
    float4 e = p[(192 + lane) * 16 + (I)];                                      \
    wo[4*(I)] = e.x; wo[4*(I)+1] = e.y; wo[4*(I)+2] = e.z; wo[4*(I)+3] = e.w; }
#define WL4(I) WL1(I) WL1((I)+1) WL1((I)+2) WL1((I)+3)
#define WLOAD WL4(0) WL4(4) WL4(8) WL4(12)

#define D1(K)                                              \
  { float hk = bcast(hv, (K));                             \
    ai = fmaf(hk, wi[(K)], ai); af = fmaf(hk, wf[(K)], af);\
    ag = fmaf(hk, wg[(K)], ag); ao = fmaf(hk, wo[(K)], ao); }
#define D8(K) D1(K) D1((K)+1) D1((K)+2) D1((K)+3) D1((K)+4) D1((K)+5) D1((K)+6) D1((K)+7)
#define DOT64 D8(0) D8(8) D8(16) D8(24) D8(32) D8(40) D8(48) D8(56)

// ---------------------------------------------------------------------------
// Kernel 1: xg1[m][n] = X[m,:].W_ih1[n,:] + b_ih1[n] + b_hh1[n]  (unchanged)
// ---------------------------------------------------------------------------
#define YW1(I) { float4 a_ = Wp[t * 32 + (I)];                                   \
    wr[4*(I)] = a_.x; wr[4*(I)+1] = a_.y; wr[4*(I)+2] = a_.z; wr[4*(I)+3] = a_.w; }
#define YW4(I) YW1(I) YW1((I)+1) YW1((I)+2) YW1((I)+3)
#define YWLOAD YW4(0) YW4(4) YW4(8) YW4(12) YW4(16) YW4(20) YW4(24) YW4(28)

#define YD1(L)                                                   \
  { float xa = bcast(curx, (L)); float xb = bcast(cury, (L));    \
    ae = fmaf(xa, wr[2*(L)], ae); ao = fmaf(xb, wr[2*(L)+1], ao); }
#define YD8(L) YD1(L) YD1((L)+1) YD1((L)+2) YD1((L)+3) YD1((L)+4) YD1((L)+5) YD1((L)+6) YD1((L)+7)
#define YDOT64 YD8(0) YD8(8) YD8(16) YD8(24) YD8(32) YD8(40) YD8(48) YD8(56)

__global__ __launch_bounds__(256, 1) void xgemm(const float* __restrict__ X,
                                                const float* __restrict__ W,
                                                const float* __restrict__ bi,
                                                const float* __restrict__ bh,
                                                float* __restrict__ XG) {
  const int t = threadIdx.x;            // 0..255 = owned W row
  const int lane = t & 63;
  const long m0 = (long)blockIdx.x * 256;

  float wr[INF];
  const float4* Wp = (const float4*)W;
  YWLOAD
  const float bias = bi[t] + bh[t];

  const float2* Xp = (const float2*)X;  // lane l holds k=2l,2l+1
  float2 cur = Xp[(size_t)m0 * 64 + lane];
  float2 nx1 = Xp[(size_t)(m0 + 1) * 64 + lane];

  for (int mi = 0; mi < 256; ++mi) {
    const long m = m0 + mi;
    float2 nx2 = make_float2(0.f, 0.f);
    if (mi + 2 < 256) nx2 = Xp[(size_t)(m + 2) * 64 + lane];

    const float curx = cur.x, cury = cur.y;
    float ae = bias, ao = 0.f;
    YDOT64
    XG[(size_t)m * GG + t] = ae + ao;
    cur = nx1; nx1 = nx2;
  }
}

// ---------------------------------------------------------------------------
// Kernel 2: 32 blocks x 8 waves = two r3 pipelines (seq A: wid 0-3, seq B:
// wid 4-7). wid&3: 0=W0 (L1 recurrence), 1=Xe, 2=Xo (Wih2 dot by parity),
// 3=W2 (L2 recurrence + store). W0_A/W0_B share SIMD0; W2_A/W2_B SIMD3.
// ---------------------------------------------------------------------------
__global__ __launch_bounds__(512, 1)
void lstm2(const float* __restrict__ XG,
           const float* __restrict__ Whh1,
           const float* __restrict__ Wih2,
           const float* __restrict__ Whh2,
           const float* __restrict__ bi2,
           const float* __restrict__ bh2,
           const float* __restrict__ m1g,
           const float* __restrict__ m2g,
           float* __restrict__ out) {
  const int bA = 2 * blockIdx.x;        // sequence for pipeline A
  const int bB = 2 * blockIdx.x + 1;    // sequence for pipeline B
  const int wid = threadIdx.x >> 6;
  const int lane = threadIdx.x & 63;

  __shared__ int f_h1A, f_xeA, f_xoA, f_2A;          // pipeline A flags
  __shared__ int f_h1B, f_xeB, f_xoB, f_2B;          // pipeline B flags
  __shared__ __align__(16) float x2bufA[8][HH];      // A: W0 -> Xe/Xo
  __shared__ __align__(16) float a2xbufA[8][GG];     // A: Xe/Xo -> W2
  __shared__ __align__(16) float x2bufB[8][HH];      // B: W0 -> Xe/Xo
  __shared__ __align__(16) float a2xbufB[8][GG];     // B: Xe/Xo -> W2

  if (threadIdx.x == 0) {
    f_h1A = 0; f_xeA = 0; f_xoA = 0; f_2A = 0;
    f_h1B = 0; f_xeB = 0; f_xoB = 0; f_2B = 0;
  }
  __syncthreads();  // one-time

// r3's proven macros, verbatim.
#define WAITC(seen, flag, tgt)                                  \
  do {                                                          \
    if ((seen) < (tgt)) {                                       \
      while (((seen) = *(volatile int*)&(flag)) < (tgt)) {}     \
    }                                                           \
    asm volatile("" ::: "memory");                              \
  } while (0)
#define PUBLISH(flag, val)                                      \
  do {                                                          \
    asm volatile("s_waitcnt lgkmcnt(0)" ::: "memory");          \
    if (lane == 0) *(volatile int*)&(flag) = (val);             \
  } while (0)

  if (wid == 0) {
    // ---- W0_A: layer-1 recurrence, sequence A ----
    float wi[HH], wf[HH], wg[HH], wo[HH];
    const float4* p = (const float4*)Whh1;
    WLOAD
    const float m1 = m1g[bA * HH + lane];
    const float* xgp = XG + (size_t)bA * TT * GG;

    float cur0 = xgp[lane], cur1 = xgp[64 + lane], cur2 = xgp[128 + lane], cur3 = xgp[192 + lane];
    float n10 = xgp[GG + lane], n11 = xgp[GG + 64 + lane], n12 = xgp[GG + 128 + lane], n13 = xgp[GG + 192 + lane];

    float h1 = 0.f, c1 = 0.f;
    int sxe = 0, sxo = 0;
    for (int s = 0; s < TT; ++s) {
      float n20 = 0.f, n21 = 0.f, n22 = 0.f, n23 = 0.f;
      if (s + 2 < TT) {
        const float* q = xgp + (size_t)(s + 2) * GG;
        n20 = q[lane]; n21 = q[64 + lane]; n22 = q[128 + lane]; n23 = q[192 + lane];
      }

      const float hv = h1;
      float ai = cur0, af = cur1, ag = cur2, ao = cur3;
      DOT64
      c1 = sigm(af) * c1 + sigm(ai) * tanh_f(ag);
      h1 = sigm(ao) * tanh_f(c1);

      if (s & 1) { WAITC(sxo, f_xoA, s - 7); }
      else       { WAITC(sxe, f_xeA, s - 7); }
      x2bufA[s & 7][lane] = h1 * m1;
      PUBLISH(f_h1A, s + 1);

      cur0 = n10; cur1 = n11; cur2 = n12; cur3 = n13;
      n10 = n20; n11 = n21; n12 = n22; n13 = n23;
    }
  } else if (wid == 3) {
    // ---- W2_A: layer-2 recurrence + store, sequence A ----
    float wi[HH], wf[HH], wg[HH], wo[HH];
    const float4* p = (const float4*)Whh2;
    WLOAD
    const float m2v = m2g[bA * HH + lane];
    float* ob = out + (size_t)bA * TT * HH;

    float h2 = 0.f, c2 = 0.f;
    int sxe = 0, sxo = 0;
    for (int s = 0; s < TT; ++s) {
      if (s & 1) { WAITC(sxo, f_xoA, s + 1); }
      else       { WAITC(sxe, f_xeA, s + 1); }
      const float pi = a2xbufA[s & 7][lane];
      const float pf = a2xbufA[s & 7][64 + lane];
      const float pg = a2xbufA[s & 7][128 + lane];
      const float po = a2xbufA[s & 7][192 + lane];

      const float hv = h2;
      float ai = 0.f, af = 0.f, ag = 0.f, ao = 0.f;
      DOT64
      ai += pi; af += pf; ag += pg; ao += po;

      c2 = sigm(af) * c2 + sigm(ai) * tanh_f(ag);
      h2 = sigm(ao) * tanh_f(c2);
      PUBLISH(f_2A, s + 1);
      ob[(size_t)s * HH + lane] = fmaxf(h2 * m2v, 0.f);
    }
  } else if (wid == 1) {
    // ---- Xe_A: Wih2 dot, even steps, sequence A ----
    float wi[HH], wf[HH], wg[HH], wo[HH];
    const float4* p = (const float4*)Wih2;
    WLOAD
    const float bi_i = bi2[lane] + bh2[lane];
    const float bi_f = bi2[64 + lane] + bh2[64 + lane];
    const float bi_g = bi2[128 + lane] + bh2[128 + lane];
    const float bi_o = bi2[192 + lane] + bh2[192 + lane];

    int s0 = 0, s2 = 0;
    for (int s = 0; s < TT; s += 2) {
      WAITC(s0, f_h1A, s + 1);
      const float hv = x2bufA[s & 7][lane];
      float ai = bi_i, af = bi_f, ag = bi_g, ao = bi_o;
      DOT64
      WAITC(s2, f_2A, s - 7);
      a2xbufA[s & 7][lane] = ai;
      a2xbufA[s & 7][64 + lane] = af;
      a2xbufA[s & 7][128 + lane] = ag;
      a2xbufA[s & 7][192 + lane] = ao;
      PUBLISH(f_xeA, s + 1);
    }
  } else if (wid == 2) {
    // ---- Xo_A: Wih2 dot, odd steps, sequence A ----
    float wi[HH], wf[HH], wg[HH], wo[HH];
    const float4* p = (const float4*)Wih2;
    WLOAD
    const float bi_i = bi2[lane] + bh2[lane];
    const float bi_f = bi2[64 + lane] + bh2[64 + lane];
    const float bi_g = bi2[128 + lane] + bh2[128 + lane];
    const float bi_o = bi2[192 + lane] + bh2[192 + lane];

    int s0 = 0, s2 = 0;
    for (int s = 1; s < TT; s += 2) {
      WAITC(s0, f_h1A, s + 1);
      const float hv = x2bufA[s & 7][lane];
      float ai = bi_i, af = bi_f, ag = bi_g, ao = bi_o;
      DOT64
      WAITC(s2, f_2A, s - 7);
      a2xbufA[s & 7][lane] = ai;
      a2xbufA[s & 7][64 + lane] = af;
      a2xbufA[s & 7][128 + lane] = ag;
      a2xbufA[s & 7][192 + lane] = ao;
      PUBLISH(f_xoA, s + 1);
    }
  } else if (wid == 4) {
    // ---- W0_B: layer-1 recurrence, sequence B (shares SIMD0 with W0_A) ----
    float wi[HH], wf[HH], wg[HH], wo[HH];
    const float4* p = (const float4*)Whh1;
    WLOAD
    const float m1 = m1g[bB * HH + lane];
    const float* xgp = XG + (size_t)bB * TT * GG;

    float cur0 = xgp[lane], cur1 = xgp[64 + lane], cur2 = xgp[128 + lane], cur3 = xgp[192 + lane];
    float n10 = xgp[GG + lane], n11 = xgp[GG + 64 + lane], n12 = xgp[GG + 128 + lane], n13 = xgp[GG + 192 + lane];

    float h1 = 0.f, c1 = 0.f;
    int sxe = 0, sxo = 0;
    for (int s = 0; s < TT; ++s) {
      float n20 = 0.f, n21 = 0.f, n22 = 0.f, n23 = 0.f;
      if (s + 2 < TT) {
        const float* q = xgp + (size_t)(s + 2) * GG;
        n20 = q[lane]; n21 = q[64 + lane]; n22 = q[128 + lane]; n23 = q[192 + lane];
      }

      const float hv = h1;
      float ai = cur0, af = cur1, ag = cur2, ao = cur3;
      DOT64
      c1 = sigm(af) * c1 + sigm(ai) * tanh_f(ag);
      h1 = sigm(ao) * tanh_f(c1);

      if (s & 1) { WAITC(sxo, f_xoB, s - 7); }
      else       { WAITC(sxe, f_xeB, s - 7); }
      x2bufB[s & 7][lane] = h1 * m1;
      PUBLISH(f_h1B, s + 1);

      cur0 = n10; cur1 = n11; cur2 = n12; cur3 = n13;
      n10 = n20; n11 = n21; n12 = n22; n13 = n23;
    }
  } else if (wid == 7) {
    // ---- W2_B: layer-2 recurrence + store, sequence B (SIMD3 w/ W2_A) ----
    float wi[HH], wf[HH], wg[HH], wo[HH];
    const float4* p = (const float4*)Whh2;
    WLOAD
    const float m2v = m2g[bB * HH + lane];
    float* ob = out + (size_t)bB * TT * HH;

    float h2 = 0.f, c2 = 0.f;
    int sxe = 0, sxo = 0;
    for (int s = 0; s < TT; ++s) {
      if (s & 1) { WAITC(sxo, f_xoB, s + 1); }
      else       { WAITC(sxe, f_xeB, s + 1); }
      const float pi = a2xbufB[s & 7][lane];
      const float pf = a2xbufB[s & 7][64 + lane];
      const float pg = a2xbufB[s & 7][128 + lane];
      const float po = a2xbufB[s & 7][192 + lane];

      const float hv = h2;
      float ai = 0.f, af = 0.f, ag = 0.f, ao = 0.f;
      DOT64
      ai += pi; af += pf; ag += pg; ao += po;

      c2 = sigm(af) * c2 + sigm(ai) * tanh_f(ag);
      h2 = sigm(ao) * tanh_f(c2);
      PUBLISH(f_2B, s + 1);
      ob[(size_t)s * HH + lane] = fmaxf(h2 * m2v, 0.f);
    }
  } else if (wid == 5) {
    // ---- Xe_B: Wih2 dot, even steps, sequence B ----
    float wi[HH], wf[HH], wg[HH], wo[HH];
    const float4* p = (const float4*)Wih2;
    WLOAD
    const float bi_i = bi2[lane] + bh2[lane];
    const float bi_f = bi2[64 + lane] + bh2[64 + lane];
    const float bi_g = bi2[128 + lane] + bh2[128 + lane];
    const float bi_o = bi2[192 + lane] + bh2[192 + lane];

    int s0 = 0, s2 = 0;
    for (int s = 0; s < TT; s += 2) {
      WAITC(s0, f_h1B, s + 1);
      const float hv = x2bufB[s & 7][lane];
      float ai = bi_i, af = bi_f, ag = bi_g, ao = bi_o;
      DOT64
      WAITC(s2, f_2B, s - 7);
      a2xbufB[s & 7][lane] = ai;
      a2xbufB[s & 7][64 + lane] = af;
      a2xbufB[s & 7][128 + lane] = ag;
      a2xbufB[s & 7][192 + lane] = ao;
      PUBLISH(f_xeB, s + 1);
    }
  } else {
    // ---- Xo_B (wid==6): Wih2 dot, odd steps, sequence B ----
    float wi[HH], wf[HH], wg[HH], wo[HH];
    const float4* p = (const float4*)Wih2;
    WLOAD
    const float bi_i = bi2[lane] + bh2[lane];
    const float bi_f = bi2[64 + lane] + bh2[64 + lane];
    const float bi_g = bi2[128 + lane] + bh2[128 + lane];
    const float bi_o = bi2[192 + lane] + bh2[192 + lane];

    int s0 = 0, s2 = 0;
    for (int s = 1; s < TT; s += 2) {
      WAITC(s0, f_h1B, s + 1);
      const float hv = x2bufB[s & 7][lane];
      float ai = bi_i, af = bi_f, ag = bi_g, ao = bi_o;
      DOT64
      WAITC(s2, f_2B, s - 7);
      a2xbufB[s & 7][lane] = ai;
      a2xbufB[s & 7][64 + lane] = af;
      a2xbufB[s & 7][128 + lane] = ag;
      a2xbufB[s & 7][192 + lane] = ao;
      PUBLISH(f_xoB, s + 1);
    }
  }
#undef WAITC
#undef PUBLISH
}

extern "C" void kernel_launch(void* const* d_in, const int* in_sizes, int n_in,
                              void* d_out, int out_size, void* d_ws, size_t ws_size,
                              hipStream_t stream) {
  (void)in_sizes; (void)n_in; (void)out_size; (void)ws_size;
  const float* x     = (const float*)d_in[0];
  const float* W_ih1 = (const float*)d_in[1];
  const float* W_hh1 = (const float*)d_in[2];
  const float* b_ih1 = (const float*)d_in[3];
  const float* b_hh1 = (const float*)d_in[4];
  const float* W_ih2 = (const float*)d_in[5];
  const float* W_hh2 = (const float*)d_in[6];
  const float* b_ih2 = (const float*)d_in[7];
  const float* b_hh2 = (const float*)d_in[8];
  const float* mask1 = (const float*)d_in[9];
  const float* mask2 = (const float*)d_in[10];
  float* out = (float*)d_out;

  float* xg1 = (float*)d_ws;  // B*T*4H fp32 = 134,217,728 bytes

  xgemm<<<dim3(BB * TT / 256), dim3(256), 0, stream>>>(x, W_ih1, b_ih1, b_hh1, xg1);
  lstm2<<<dim3(BB / 2), dim3(512), 0, stream>>>(xg1, W_hh1, W_ih2, W_hh2,
                                                b_ih2, b_hh2, mask1, mask2, out);
}

// Round 11
// 2903.290 us; speedup vs baseline: 1.6460x; 1.6460x over previous
//
#include <hip/hip_runtime.h>
#include <hip/hip_bf16.h>

// Problem constants: B=64, T=2048, IN_F=128, H1=OUT_F=64, 4H=256
#define BB 64
#define TT 2048
#define INF 128
#define HH 64
#define GG 256  // 4*H

__device__ __forceinline__ float sigm(float x) { return 1.0f / (1.0f + __expf(-x)); }
__device__ __forceinline__ float tanh_f(float x) {
  float e = __expf(2.0f * x);
  return 1.0f - 2.0f / (e + 1.0f);
}
// Wave-uniform broadcast of lane l's value via v_readlane (SGPR path, no LDS).
__device__ __forceinline__ float bcast(float v, int l) {
  return __uint_as_float(__builtin_amdgcn_readlane(__float_as_uint(v), l));
}
// Cell update shared by BOTH waves of a team: same inline DAG, same published
// fp32 inputs -> bit-identical redundant (h,c). (Validated in round 2.)
__device__ __forceinline__ void lstm_upd(float Si, float Sf, float Tg, float So,
                                         float& c, float& h) {
  c = fmaf(Sf, c, Si * Tg);
  h = So * tanh_f(c);
}

// ---------------------------------------------------------------------------
// Round-10 bench died to a container/infra failure (no compile or perf
// verdict). Deadlock audit came back clean (publish-before-wait + lgkm-drain
// ordering; all flag graphs monotone/acyclic; ring waits start satisfied).
// Resubmitting unchanged.
//
// Round-9 verdict: recurrence waves SATURATE their SIMD (2 co-resident waves
// = exactly 2x time), at ~2480cy/step vs ~780cy of source VALU -> the weight
// arrays are never cleanly register-resident (VGPR_Count 144 @ 256 floats;
// 80 @ 128 floats in r2; 204 with none in r5) and every fma pays a spill tax.
// Round 10/11: NO wave holds more than 128 weight floats, full overlap kept:
//   64 blocks x 8 waves (wid&3 = SIMD):
//     wid0 S0: W0if  L1 gates i,f  + x2 publish      (128 w-floats)
//     wid1 S1: W0go  L1 gates g,o                    (128)
//     wid2 S2: W2if  L2 gates i,f  + out store       (128)
//     wid3 S3: W2go  L2 gates g,o                    (128)
//     wid4 S0: Xif_e Wih2 i,f, even steps            (128)
//     wid5 S1: Xif_o Wih2 i,f, odd  steps            (128)
//     wid6 S2: Xgo_e Wih2 g,o, even steps            (128)
//     wid7 S3: Xgo_o Wih2 g,o, odd  steps            (128)
//   Each SIMD: one W wave (~full step) + one X wave (~1/4 step) - balanced.
//   Teams exchange activated gate pairs symmetrically (r2-validated, 1
//   parallel LDS hop/step); 2-deep ex buffers are race-free via the
//   publish-before-wait + lgkmcnt(0)-drain ordering.
// All construct classes verbatim from compiled rounds (r2 dot macros,
// r3/r9 WAITC/PUBLISH, statically named LDS arrays/flags).
// Per-gate k-accumulation order unchanged -> same numerics as r0-r5.
// ---------------------------------------------------------------------------

// 2-gate weight load: lane owns row (base+lane) -> wA, row (base+64+lane) -> wB.
// p = (const float4*)(W + base*HH); row = 16 float4.  (r2-verbatim)
#define WL2(I)                                                                   \
  { float4 a_ = p[lane * 16 + (I)];                                              \
    wA[4*(I)] = a_.x; wA[4*(I)+1] = a_.y; wA[4*(I)+2] = a_.z; wA[4*(I)+3] = a_.w;\
    float4 b_ = p[(64 + lane) * 16 + (I)];                                       \
    wB[4*(I)] = b_.x; wB[4*(I)+1] = b_.y; wB[4*(I)+2] = b_.z; wB[4*(I)+3] = b_.w; }
#define WL2x4(I) WL2(I) WL2((I)+1) WL2((I)+2) WL2((I)+3)
#define WLOAD2 WL2x4(0) WL2x4(4) WL2x4(8) WL2x4(12)

#define G1(K)                                                    \
  { float hk = bcast(hv, (K));                                   \
    aA = fmaf(hk, wA[(K)], aA); aB = fmaf(hk, wB[(K)], aB); }
#define G8(K) G1(K) G1((K)+1) G1((K)+2) G1((K)+3) G1((K)+4) G1((K)+5) G1((K)+6) G1((K)+7)
#define DOT2G G8(0) G8(8) G8(16) G8(24) G8(32) G8(40) G8(48) G8(56)

// ---------------------------------------------------------------------------
// Kernel 1: xg1[m][n] = X[m,:].W_ih1[n,:] + b_ih1[n] + b_hh1[n]  (unchanged)
// ---------------------------------------------------------------------------
#define YW1(I) { float4 a_ = Wp[t * 32 + (I)];                                   \
    wr[4*(I)] = a_.x; wr[4*(I)+1] = a_.y; wr[4*(I)+2] = a_.z; wr[4*(I)+3] = a_.w; }
#define YW4(I) YW1(I) YW1((I)+1) YW1((I)+2) YW1((I)+3)
#define YWLOAD YW4(0) YW4(4) YW4(8) YW4(12) YW4(16) YW4(20) YW4(24) YW4(28)

#define YD1(L)                                                   \
  { float xa = bcast(curx, (L)); float xb = bcast(cury, (L));    \
    ae = fmaf(xa, wr[2*(L)], ae); ao = fmaf(xb, wr[2*(L)+1], ao); }
#define YD8(L) YD1(L) YD1((L)+1) YD1((L)+2) YD1((L)+3) YD1((L)+4) YD1((L)+5) YD1((L)+6) YD1((L)+7)
#define YDOT64 YD8(0) YD8(8) YD8(16) YD8(24) YD8(32) YD8(40) YD8(48) YD8(56)

__global__ __launch_bounds__(256, 1) void xgemm(const float* __restrict__ X,
                                                const float* __restrict__ W,
                                                const float* __restrict__ bi,
                                                const float* __restrict__ bh,
                                                float* __restrict__ XG) {
  const int t = threadIdx.x;            // 0..255 = owned W row
  const int lane = t & 63;
  const long m0 = (long)blockIdx.x * 256;

  float wr[INF];
  const float4* Wp = (const float4*)W;
  YWLOAD
  const float bias = bi[t] + bh[t];

  const float2* Xp = (const float2*)X;  // lane l holds k=2l,2l+1
  float2 cur = Xp[(size_t)m0 * 64 + lane];
  float2 nx1 = Xp[(size_t)(m0 + 1) * 64 + lane];

  for (int mi = 0; mi < 256; ++mi) {
    const long m = m0 + mi;
    float2 nx2 = make_float2(0.f, 0.f);
    if (mi + 2 < 256) nx2 = Xp[(size_t)(m + 2) * 64 + lane];

    const float curx = cur.x, cury = cur.y;
    float ae = bias, ao = 0.f;
    YDOT64
    XG[(size_t)m * GG + t] = ae + ao;
    cur = nx1; nx1 = nx2;
  }
}

// ---------------------------------------------------------------------------
// Kernel 2: 64 blocks x 8 waves (512 threads), one sequence per block.
// ---------------------------------------------------------------------------
__global__ __launch_bounds__(512, 1)
void lstm2(const float* __restrict__ XG,
           const float* __restrict__ Whh1,
           const float* __restrict__ Wih2,
           const float* __restrict__ Whh2,
           const float* __restrict__ bi2,
           const float* __restrict__ bh2,
           const float* __restrict__ m1g,
           const float* __restrict__ m2g,
           float* __restrict__ out) {
  const int b = blockIdx.x;
  const int wid = threadIdx.x >> 6;
  const int lane = threadIdx.x & 63;

  __shared__ int f_0A, f_0B;                         // L1 team exchange
  __shared__ int f_2A, f_2B;                         // L2 team exchange
  __shared__ int f_h1;                               // W0if -> X waves
  __shared__ int f_xife, f_xifo, f_xgoe, f_xgoo;     // X -> W2 rings
  __shared__ __align__(16) float ex0A[2][2 * HH];    // W0if -> W0go: Si,Sf
  __shared__ __align__(16) float ex0B[2][2 * HH];    // W0go -> W0if: Tg,So
  __shared__ __align__(16) float ex2A[2][2 * HH];    // W2if -> W2go: Si,Sf
  __shared__ __align__(16) float ex2B[2][2 * HH];    // W2go -> W2if: Tg,So
  __shared__ __align__(16) float x2buf[8][HH];       // W0if -> X waves
  __shared__ __align__(16) float a2xif[8][2 * HH];   // Xif -> W2if: ai,af
  __shared__ __align__(16) float a2xgo[8][2 * HH];   // Xgo -> W2go: ag,ao

  if (threadIdx.x == 0) {
    f_0A = 0; f_0B = 0; f_2A = 0; f_2B = 0; f_h1 = 0;
    f_xife = 0; f_xifo = 0; f_xgoe = 0; f_xgoo = 0;
  }
  __syncthreads();  // one-time

// r3/r9's proven macros, verbatim.
#define WAITC(seen, flag, tgt)                                  \
  do {                                                          \
    if ((seen) < (tgt)) {                                       \
      while (((seen) = *(volatile int*)&(flag)) < (tgt)) {}     \
    }                                                           \
    asm volatile("" ::: "memory");                              \
  } while (0)
#define PUBLISH(flag, val)                                      \
  do {                                                          \
    asm volatile("s_waitcnt lgkmcnt(0)" ::: "memory");          \
    if (lane == 0) *(volatile int*)&(flag) = (val);             \
  } while (0)

  if (wid == 0) {
    // ---- W0if (S0): L1 gates i,f; owns x2 publish ----
    float wA[HH], wB[HH];
    const float4* p = (const float4*)Whh1;            // rows 0..127 (i,f)
    WLOAD2
    const float m1 = m1g[b * HH + lane];
    const float* xgp = XG + (size_t)b * TT * GG;

    float xi0 = xgp[lane],      xf0 = xgp[64 + lane];
    float xi1 = xgp[GG + lane], xf1 = xgp[GG + 64 + lane];

    float h1 = 0.f, c1 = 0.f;
    int s0B = 0, se1 = 0, se2 = 0, so1 = 0, so2 = 0;
    for (int s = 0; s < TT; ++s) {
      float xi2 = 0.f, xf2 = 0.f;
      if (s + 2 < TT) {
        const float* q = xgp + (size_t)(s + 2) * GG;
        xi2 = q[lane]; xf2 = q[64 + lane];
      }
      const float hv = h1;
      float aA = xi0, aB = xf0;
      DOT2G
      const float Si = sigm(aA), Sf = sigm(aB);
      ex0A[s & 1][lane] = Si; ex0A[s & 1][64 + lane] = Sf;
      PUBLISH(f_0A, s + 1);              // publish BEFORE waiting
      WAITC(s0B, f_0B, s + 1);
      const float Tg = ex0B[s & 1][lane], So = ex0B[s & 1][64 + lane];
      lstm_upd(Si, Sf, Tg, So, c1, h1);
      // x2 ring slot (s&7): prev occupant s-8 (same parity) consumed when
      // both matching-parity X waves published s-7. Cached in steady state.
      if (s & 1) { WAITC(so1, f_xifo, s - 7); WAITC(so2, f_xgoo, s - 7); }
      else       { WAITC(se1, f_xife, s - 7); WAITC(se2, f_xgoe, s - 7); }
      x2buf[s & 7][lane] = h1 * m1;
      PUBLISH(f_h1, s + 1);
      xi0 = xi1; xf0 = xf1; xi1 = xi2; xf1 = xf2;
    }
  } else if (wid == 1) {
    // ---- W0go (S1): L1 gates g,o ----
    float wA[HH], wB[HH];
    const float4* p = (const float4*)(Whh1 + 128 * HH);  // rows 128..255 (g,o)
    WLOAD2
    const float* xgp = XG + (size_t)b * TT * GG;

    float xg0 = xgp[128 + lane],      xo0 = xgp[192 + lane];
    float xg1 = xgp[GG + 128 + lane], xo1 = xgp[GG + 192 + lane];

    float h1 = 0.f, c1 = 0.f;
    int s0A = 0;
    for (int s = 0; s < TT; ++s) {
      float xg2 = 0.f, xo2 = 0.f;
      if (s + 2 < TT) {
        const float* q = xgp + (size_t)(s + 2) * GG;
        xg2 = q[128 + lane]; xo2 = q[192 + lane];
      }
      const float hv = h1;
      float aA = xg0, aB = xo0;
      DOT2G
      const float Tg = tanh_f(aA), So = sigm(aB);
      ex0B[s & 1][lane] = Tg; ex0B[s & 1][64 + lane] = So;
      PUBLISH(f_0B, s + 1);
      WAITC(s0A, f_0A, s + 1);
      const float Si = ex0A[s & 1][lane], Sf = ex0A[s & 1][64 + lane];
      lstm_upd(Si, Sf, Tg, So, c1, h1);
      xg0 = xg1; xo0 = xo1; xg1 = xg2; xo1 = xo2;
    }
  } else if (wid == 2) {
    // ---- W2if (S2): L2 gates i,f; owns out store ----
    float wA[HH], wB[HH];
    const float4* p = (const float4*)Whh2;               // rows 0..127 (i,f)
    WLOAD2
    const float m2v = m2g[b * HH + lane];
    float* ob = out + (size_t)b * TT * HH;

    float h2 = 0.f, c2 = 0.f;
    int sxe = 0, sxo = 0, s2B = 0;
    for (int s = 0; s < TT; ++s) {
      if (s & 1) { WAITC(sxo, f_xifo, s + 1); }
      else       { WAITC(sxe, f_xife, s + 1); }
      const float pi = a2xif[s & 7][lane];               // issue early
      const float pf = a2xif[s & 7][64 + lane];
      const float hv = h2;
      float aA = 0.f, aB = 0.f;
      DOT2G                       // ring-read latency hides under the dot
      aA += pi; aB += pf;
      const float Si = sigm(aA), Sf = sigm(aB);
      ex2A[s & 1][lane] = Si; ex2A[s & 1][64 + lane] = Sf;
      PUBLISH(f_2A, s + 1);       // lgkm drain => a2xif slot s consumed too
      WAITC(s2B, f_2B, s + 1);
      const float Tg = ex2B[s & 1][lane], So = ex2B[s & 1][64 + lane];
      lstm_upd(Si, Sf, Tg, So, c2, h2);
      ob[(size_t)s * HH + lane] = fmaxf(h2 * m2v, 0.f);
    }
  } else if (wid == 3) {
    // ---- W2go (S3): L2 gates g,o ----
    float wA[HH], wB[HH];
    const float4* p = (const float4*)(Whh2 + 128 * HH);  // rows 128..255 (g,o)
    WLOAD2

    float h2 = 0.f, c2 = 0.f;
    int sxe = 0, sxo = 0, s2A = 0;
    for (int s = 0; s < TT; ++s) {
      if (s & 1) { WAITC(sxo, f_xgoo, s + 1); }
      else       { WAITC(sxe, f_xgoe, s + 1); }
      const float pg = a2xgo[s & 7][lane];
      const float po = a2xgo[s & 7][64 + lane];
      const float hv = h2;
      float aA = 0.f, aB = 0.f;
      DOT2G
      aA += pg; aB += po;
      const float Tg = tanh_f(aA), So = sigm(aB);
      ex2B[s & 1][lane] = Tg; ex2B[s & 1][64 + lane] = So;
      PUBLISH(f_2B, s + 1);       // lgkm drain => a2xgo slot s consumed too
      WAITC(s2A, f_2A, s + 1);
      const float Si = ex2A[s & 1][lane], Sf = ex2A[s & 1][64 + lane];
      lstm_upd(Si, Sf, Tg, So, c2, h2);
    }
  } else if (wid == 4) {
    // ---- Xif_e (S0): Wih2 gates i,f, even steps ----
    float wA[HH], wB[HH];
    const float4* p = (const float4*)Wih2;               // rows 0..127 (i,f)
    WLOAD2
    const float biA = bi2[lane] + bh2[lane];
    const float biB = bi2[64 + lane] + bh2[64 + lane];

    int s0 = 0, sc = 0;
    for (int s = 0; s < TT; s += 2) {
      WAITC(s0, f_h1, s + 1);
      const float hv = x2buf[s & 7][lane];
      float aA = biA, aB = biB;
      DOT2G
      WAITC(sc, f_2A, s - 7);     // a2xif slot (s&7) free? prev occupant s-8
      a2xif[s & 7][lane] = aA; a2xif[s & 7][64 + lane] = aB;
      PUBLISH(f_xife, s + 1);     // lgkm drain => x2buf read complete
    }
  } else if (wid == 5) {
    // ---- Xif_o (S1): Wih2 gates i,f, odd steps ----
    float wA[HH], wB[HH];
    const float4* p = (const float4*)Wih2;
    WLOAD2
    const float biA = bi2[lane] + bh2[lane];
    const float biB = bi2[64 + lane] + bh2[64 + lane];

    int s0 = 0, sc = 0;
    for (int s = 1; s < TT; s += 2) {
      WAITC(s0, f_h1, s + 1);
      const float hv = x2buf[s & 7][lane];
      float aA = biA, aB = biB;
      DOT2G
      WAITC(sc, f_2A, s - 7);
      a2xif[s & 7][lane] = aA; a2xif[s & 7][64 + lane] = aB;
      PUBLISH(f_xifo, s + 1);
    }
  } else if (wid == 6) {
    // ---- Xgo_e (S2): Wih2 gates g,o, even steps ----
    float wA[HH], wB[HH];
    const float4* p = (const float4*)(Wih2 + 128 * HH);  // rows 128..255 (g,o)
    WLOAD2
    const float biA = bi2[128 + lane] + bh2[128 + lane];
    const float biB = bi2[192 + lane] + bh2[192 + lane];

    int s0 = 0, sc = 0;
    for (int s = 0; s < TT; s += 2) {
      WAITC(s0, f_h1, s + 1);
      const float hv = x2buf[s & 7][lane];
      float aA = biA, aB = biB;
      DOT2G
      WAITC(sc, f_2B, s - 7);     // a2xgo slot free per W2go's counter
      a2xgo[s & 7][lane] = aA; a2xgo[s & 7][64 + lane] = aB;
      PUBLISH(f_xgoe, s + 1);
    }
  } else {
    // ---- Xgo_o (wid==7, S3): Wih2 gates g,o, odd steps ----
    float wA[HH], wB[HH];
    const float4* p = (const float4*)(Wih2 + 128 * HH);
    WLOAD2
    const float biA = bi2[128 + lane] + bh2[128 + lane];
    const float biB = bi2[192 + lane] + bh2[192 + lane];

    int s0 = 0, sc = 0;
    for (int s = 1; s < TT; s += 2) {
      WAITC(s0, f_h1, s + 1);
      const float hv = x2buf[s & 7][lane];
      float aA = biA, aB = biB;
      DOT2G
      WAITC(sc, f_2B, s - 7);
      a2xgo[s & 7][lane] = aA; a2xgo[s & 7][64 + lane] = aB;
      PUBLISH(f_xgoo, s + 1);
    }
  }
#undef WAITC
#undef PUBLISH
}

extern "C" void kernel_launch(void* const* d_in, const int* in_sizes, int n_in,
                              void* d_out, int out_size, void* d_ws, size_t ws_size,
                              hipStream_t stream) {
  (void)in_sizes; (void)n_in; (void)out_size; (void)ws_size;
  const float* x     = (const float*)d_in[0];
  const float* W_ih1 = (const float*)d_in[1];
  const float* W_hh1 = (const float*)d_in[2];
  const float* b_ih1 = (const float*)d_in[3];
  const float* b_hh1 = (const float*)d_in[4];
  const float* W_ih2 = (const float*)d_in[5];
  const float* W_hh2 = (const float*)d_in[6];
  const float* b_ih2 = (const float*)d_in[7];
  const float* b_hh2 = (const float*)d_in[8];
  const float* mask1 = (const float*)d_in[9];
  const float* mask2 = (const float*)d_in[10];
  float* out = (float*)d_out;

  float* xg1 = (float*)d_ws;  // B*T*4H fp32 = 134,217,728 bytes

  xgemm<<<dim3(BB * TT / 256), dim3(256), 0, stream>>>(x, W_ih1, b_ih1, b_hh1, xg1);
  lstm2<<<dim3(BB), dim3(512), 0, stream>>>(xg1, W_hh1, W_ih2, W_hh2,
                                            b_ih2, b_hh2, mask1, mask2, out);
}

// Round 12
// 2657.373 us; speedup vs baseline: 1.7983x; 1.0925x over previous
//
#include <hip/hip_runtime.h>
#include <hip/hip_bf16.h>

// Problem constants: B=64, T=2048, IN_F=128, H1=OUT_F=64, 4H=256
#define BB 64
#define TT 2048
#define INF 128
#define HH 64
#define GG 256  // 4*H

typedef float v2f __attribute__((ext_vector_type(2)));
__device__ __forceinline__ v2f mk2(float x, float y) { v2f r; r.x = x; r.y = y; return r; }
#if __has_builtin(__builtin_elementwise_fma)
#define VFMA(a, b, c) __builtin_elementwise_fma((a), (b), (c))
#else
#define VFMA(a, b, c) ((a) * (b) + (c))   // -ffp-contract=fast -> pk_fma
#endif

__device__ __forceinline__ float sigm(float x) { return 1.0f / (1.0f + __expf(-x)); }
__device__ __forceinline__ float tanh_f(float x) {
  float e = __expf(2.0f * x);
  return 1.0f - 2.0f / (e + 1.0f);
}
// Wave-uniform broadcast of lane l's value via v_readlane (xgemm only now).
__device__ __forceinline__ float bcast(float v, int l) {
  return __uint_as_float(__builtin_amdgcn_readlane(__float_as_uint(v), l));
}

// ---------------------------------------------------------------------------
// Rounds 0-11 ledger: step time (~2480cy) is INSENSITIVE to dot size (576 vs
// 320 inst dots identical) and to weight location (regs/L2/LDS all >= 2480);
// recurrence waves saturate their SIMD (r9: 2 waves = 2x). Remaining suspect:
// the 64 v_readlane->SGPR->v_fma hazards per dot (VALU-SGPR wait states
// occupy issue slots -> looks like saturation, scales with k-count not
// weight-count - consistent with ALL measurements). Round 12: eliminate
// readlane entirely (h replicated via lane-uniform ds_read_b128 broadcasts,
// 16 per dot) + packed fp32 (v_pk_fma_f32, 128 per dot). Dot = 144 insts,
// zero SGPR hazards. Topology = r3's (best measured, 2118us).
// Numerics: per-gate k-accumulation order unchanged, fma semantics kept
// (elementwise_fma) -> matches r0-r5 bit-for-bit.
// ---------------------------------------------------------------------------

// pk weight load: 4 gates as v2f pairs wIF[k]={wi,wf}, wGO[k]={wg,wo}.
#define PWL(I)                                                                  \
  { float4 a_ = p[lane * 16 + (I)];        /* wi */                             \
    float4 c_ = p[(64 + lane) * 16 + (I)]; /* wf */                             \
    float4 d_ = p[(128 + lane) * 16 + (I)];/* wg */                             \
    float4 e_ = p[(192 + lane) * 16 + (I)];/* wo */                             \
    wIF[4*(I)]   = mk2(a_.x, c_.x); wGO[4*(I)]   = mk2(d_.x, e_.x);             \
    wIF[4*(I)+1] = mk2(a_.y, c_.y); wGO[4*(I)+1] = mk2(d_.y, e_.y);             \
    wIF[4*(I)+2] = mk2(a_.z, c_.z); wGO[4*(I)+2] = mk2(d_.z, e_.z);             \
    wIF[4*(I)+3] = mk2(a_.w, c_.w); wGO[4*(I)+3] = mk2(d_.w, e_.w); }
#define PWL4(I) PWL(I) PWL((I)+1) PWL((I)+2) PWL((I)+3)
#define PWLOAD PWL4(0) PWL4(4) PWL4(8) PWL4(12)

// pk dot quad: one lane-uniform float4 LDS broadcast -> 4 k's -> 8 pk_fma.
#define PKQ(J)                                                        \
  { const float4 hq = hb[(J)];                                        \
    const v2f h0 = mk2(hq.x, hq.x), h1 = mk2(hq.y, hq.y);             \
    const v2f h2 = mk2(hq.z, hq.z), h3 = mk2(hq.w, hq.w);             \
    aIF = VFMA(h0, wIF[4*(J)],   aIF); aGO = VFMA(h0, wGO[4*(J)],   aGO); \
    aIF = VFMA(h1, wIF[4*(J)+1], aIF); aGO = VFMA(h1, wGO[4*(J)+1], aGO); \
    aIF = VFMA(h2, wIF[4*(J)+2], aIF); aGO = VFMA(h2, wGO[4*(J)+2], aGO); \
    aIF = VFMA(h3, wIF[4*(J)+3], aIF); aGO = VFMA(h3, wGO[4*(J)+3], aGO); }
#define PKDOT PKQ(0) PKQ(1) PKQ(2) PKQ(3) PKQ(4) PKQ(5) PKQ(6) PKQ(7)   \
              PKQ(8) PKQ(9) PKQ(10) PKQ(11) PKQ(12) PKQ(13) PKQ(14) PKQ(15)

// ---------------------------------------------------------------------------
// Kernel 1: xg1[m][n] = X[m,:].W_ih1[n,:] + b_ih1[n] + b_hh1[n]
// pk version: wp[L] = {wr[2L], wr[2L+1]}; acc2 = {even-k chain, odd-k chain}.
// Same accumulation order as before -> identical numerics.
// ---------------------------------------------------------------------------
#define YW1(I) { float4 a_ = Wp[t * 32 + (I)];                                   \
    wp[2*(I)] = mk2(a_.x, a_.y); wp[2*(I)+1] = mk2(a_.z, a_.w); }
#define YW4(I) YW1(I) YW1((I)+1) YW1((I)+2) YW1((I)+3)
#define YWLOAD YW4(0) YW4(4) YW4(8) YW4(12) YW4(16) YW4(20) YW4(24) YW4(28)

#define YD1(L)                                                   \
  { float xa = bcast(curx, (L)); float xb = bcast(cury, (L));    \
    acc2 = VFMA(mk2(xa, xb), wp[(L)], acc2); }
#define YD8(L) YD1(L) YD1((L)+1) YD1((L)+2) YD1((L)+3) YD1((L)+4) YD1((L)+5) YD1((L)+6) YD1((L)+7)
#define YDOT64 YD8(0) YD8(8) YD8(16) YD8(24) YD8(32) YD8(40) YD8(48) YD8(56)

__global__ __launch_bounds__(256, 1) void xgemm(const float* __restrict__ X,
                                                const float* __restrict__ W,
                                                const float* __restrict__ bi,
                                                const float* __restrict__ bh,
                                                float* __restrict__ XG) {
  const int t = threadIdx.x;            // 0..255 = owned W row
  const int lane = t & 63;
  const long m0 = (long)blockIdx.x * 256;

  v2f wp[64];
  const float4* Wp = (const float4*)W;
  YWLOAD
  const float bias = bi[t] + bh[t];

  const float2* Xp = (const float2*)X;  // lane l holds k=2l,2l+1
  float2 cur = Xp[(size_t)m0 * 64 + lane];
  float2 nx1 = Xp[(size_t)(m0 + 1) * 64 + lane];

  for (int mi = 0; mi < 256; ++mi) {
    const long m = m0 + mi;
    float2 nx2 = make_float2(0.f, 0.f);
    if (mi + 2 < 256) nx2 = Xp[(size_t)(m + 2) * 64 + lane];

    const float curx = cur.x, cury = cur.y;
    v2f acc2 = mk2(bias, 0.f);
    YDOT64
    XG[(size_t)m * GG + t] = acc2.x + acc2.y;
    cur = nx1; nx1 = nx2;
  }
}

// ---------------------------------------------------------------------------
// Kernel 2: r3 topology - 64 blocks x 4 waves, one wave per SIMD.
//  wid 0: W0  L1 recurrence (pk dot, h via hrep1 LDS broadcast) -> x2 ring
//  wid 1: Xe  Wih2 pk dot over x2 broadcast, even steps -> a2x ring
//  wid 2: Xo  ... odd steps -> a2x ring
//  wid 3: W2  L2 recurrence (pk dot, hrep2), a2x pre-read, store
// ---------------------------------------------------------------------------
__global__ __launch_bounds__(256, 1)
void lstm2(const float* __restrict__ XG,
           const float* __restrict__ Whh1,
           const float* __restrict__ Wih2,
           const float* __restrict__ Whh2,
           const float* __restrict__ bi2,
           const float* __restrict__ bh2,
           const float* __restrict__ m1g,
           const float* __restrict__ m2g,
           float* __restrict__ out) {
  const int b = blockIdx.x;
  const int wid = threadIdx.x >> 6;
  const int lane = threadIdx.x & 63;

  __shared__ int f_h1, f_xe, f_xo, f_2;             // monotonic step counters
  __shared__ __align__(16) float x2buf[8][HH];      // W0 -> Xe/Xo ring (masked h)
  __shared__ __align__(16) float a2xbuf[8][GG];     // Xe/Xo -> W2 ring
  __shared__ __align__(16) float hrep1[2][HH];      // W0 self: raw h1 ring
  __shared__ __align__(16) float hrep2[2][HH];      // W2 self: raw h2 ring

  if (threadIdx.x == 0) { f_h1 = 0; f_xe = 0; f_xo = 0; f_2 = 0; }
  __syncthreads();  // one-time

// r3's proven macros, verbatim.
#define WAITC(seen, flag, tgt)                                  \
  do {                                                          \
    if ((seen) < (tgt)) {                                       \
      while (((seen) = *(volatile int*)&(flag)) < (tgt)) {}     \
    }                                                           \
    asm volatile("" ::: "memory");                              \
  } while (0)
#define PUBLISH(flag, val)                                      \
  do {                                                          \
    asm volatile("s_waitcnt lgkmcnt(0)" ::: "memory");          \
    if (lane == 0) *(volatile int*)&(flag) = (val);             \
  } while (0)

  if (wid == 0) {
    // ---- W0: layer-1 recurrence, pk dot, zero readlanes ----
    v2f wIF[HH], wGO[HH];
    const float4* p = (const float4*)Whh1;
    PWLOAD
    const float m1 = m1g[b * HH + lane];
    const float* xgp = XG + (size_t)b * TT * GG;

    hrep1[0][lane] = 0.f;                 // h(-1) = 0 (self-ordered via DS)

    float cur0 = xgp[lane], cur1 = xgp[64 + lane], cur2 = xgp[128 + lane], cur3 = xgp[192 + lane];
    float n10 = xgp[GG + lane], n11 = xgp[GG + 64 + lane], n12 = xgp[GG + 128 + lane], n13 = xgp[GG + 192 + lane];

    float h1 = 0.f, c1 = 0.f;
    int sxe = 0, sxo = 0;
    for (int s = 0; s < TT; ++s) {
      float n20 = 0.f, n21 = 0.f, n22 = 0.f, n23 = 0.f;
      if (s + 2 < TT) {
        const float* q = xgp + (size_t)(s + 2) * GG;
        n20 = q[lane]; n21 = q[64 + lane]; n22 = q[128 + lane]; n23 = q[192 + lane];
      }

      const float4* hb = (const float4*)(&hrep1[s & 1][0]);  // h(s-1), broadcast
      v2f aIF = mk2(cur0, cur1), aGO = mk2(cur2, cur3);
      PKDOT
      c1 = sigm(aIF.y) * c1 + sigm(aIF.x) * tanh_f(aGO.x);
      h1 = sigm(aGO.y) * tanh_f(c1);

      if (s & 1) { WAITC(sxo, f_xo, s - 7); }
      else       { WAITC(sxe, f_xe, s - 7); }
      x2buf[s & 7][lane] = h1 * m1;
      hrep1[(s + 1) & 1][lane] = h1;       // raw h for own next-step dot
      PUBLISH(f_h1, s + 1);                // lgkm drain orders everything

      cur0 = n10; cur1 = n11; cur2 = n12; cur3 = n13;
      n10 = n20; n11 = n21; n12 = n22; n13 = n23;
    }
  } else if (wid == 3) {
    // ---- W2: layer-2 recurrence, pk dot, zero readlanes ----
    v2f wIF[HH], wGO[HH];
    const float4* p = (const float4*)Whh2;
    PWLOAD
    const float m2v = m2g[b * HH + lane];
    float* ob = out + (size_t)b * TT * HH;

    hrep2[0][lane] = 0.f;

    float h2 = 0.f, c2 = 0.f;
    int sxe = 0, sxo = 0;
    for (int s = 0; s < TT; ++s) {
      if (s & 1) { WAITC(sxo, f_xo, s + 1); }
      else       { WAITC(sxe, f_xe, s + 1); }
      // issue the 4 per-lane ring reads NOW; latency hides under the dot
      const float pi = a2xbuf[s & 7][lane];
      const float pf = a2xbuf[s & 7][64 + lane];
      const float pg = a2xbuf[s & 7][128 + lane];
      const float po = a2xbuf[s & 7][192 + lane];

      const float4* hb = (const float4*)(&hrep2[s & 1][0]);
      v2f aIF = mk2(0.f, 0.f), aGO = mk2(0.f, 0.f);
      PKDOT
      aIF = aIF + mk2(pi, pf);
      aGO = aGO + mk2(pg, po);

      c2 = sigm(aIF.y) * c2 + sigm(aIF.x) * tanh_f(aGO.x);
      h2 = sigm(aGO.y) * tanh_f(c2);
      hrep2[(s + 1) & 1][lane] = h2;
      PUBLISH(f_2, s + 1);    // lgkm drain -> a2x slot consumed + hrep ordered
      ob[(size_t)s * HH + lane] = fmaxf(h2 * m2v, 0.f);
    }
  } else {
    // ---- Xe (wid 1) / Xo (wid 2): Wih2 pk dot over x2 broadcast ----
    v2f wIF[HH], wGO[HH];
    const float4* p = (const float4*)Wih2;
    PWLOAD
    const float bi_i = bi2[lane] + bh2[lane];
    const float bi_f = bi2[64 + lane] + bh2[64 + lane];
    const float bi_g = bi2[128 + lane] + bh2[128 + lane];
    const float bi_o = bi2[192 + lane] + bh2[192 + lane];

    const int par = wid - 1;                       // 0 = even steps, 1 = odd
    int s0 = 0, s2 = 0;
    for (int s = par; s < TT; s += 2) {
      WAITC(s0, f_h1, s + 1);
      const float4* hb = (const float4*)(&x2buf[s & 7][0]);  // broadcast reads
      v2f aIF = mk2(bi_i, bi_f), aGO = mk2(bi_g, bi_o);
      PKDOT

      WAITC(s2, f_2, s - 7);   // a2x slot (s&7) free? prev occupant s-8.
      a2xbuf[s & 7][lane] = aIF.x;
      a2xbuf[s & 7][64 + lane] = aIF.y;
      a2xbuf[s & 7][128 + lane] = aGO.x;
      a2xbuf[s & 7][192 + lane] = aGO.y;
      if (par) { PUBLISH(f_xo, s + 1); }
      else     { PUBLISH(f_xe, s + 1); }
    }
  }
#undef WAITC
#undef PUBLISH
}

extern "C" void kernel_launch(void* const* d_in, const int* in_sizes, int n_in,
                              void* d_out, int out_size, void* d_ws, size_t ws_size,
                              hipStream_t stream) {
  (void)in_sizes; (void)n_in; (void)out_size; (void)ws_size;
  const float* x     = (const float*)d_in[0];
  const float* W_ih1 = (const float*)d_in[1];
  const float* W_hh1 = (const float*)d_in[2];
  const float* b_ih1 = (const float*)d_in[3];
  const float* b_hh1 = (const float*)d_in[4];
  const float* W_ih2 = (const float*)d_in[5];
  const float* W_hh2 = (const float*)d_in[6];
  const float* b_ih2 = (const float*)d_in[7];
  const float* b_hh2 = (const float*)d_in[8];
  const float* mask1 = (const float*)d_in[9];
  const float* mask2 = (const float*)d_in[10];
  float* out = (float*)d_out;

  float* xg1 = (float*)d_ws;  // B*T*4H fp32 = 134,217,728 bytes

  xgemm<<<dim3(BB * TT / 256), dim3(256), 0, stream>>>(x, W_ih1, b_ih1, b_hh1, xg1);
  lstm2<<<dim3(BB), dim3(256), 0, stream>>>(xg1, W_hh1, W_ih2, W_hh2,
                                            b_ih2, b_hh2, mask1, mask2, out);
}